// Round 17
// baseline (217.853 us; speedup 1.0000x reference)
//
#include <hip/hip_runtime.h>
#include <hip/hip_bf16.h>

typedef _Float16 f16;
typedef __attribute__((ext_vector_type(8))) _Float16 f16x8;
typedef __attribute__((ext_vector_type(4))) _Float16 f16x4;
typedef __attribute__((ext_vector_type(4))) float f32x4;

#define MFMA16(a, b, c) __builtin_amdgcn_mfma_f32_16x16x32_f16((a), (b), (c), 0, 0, 0)

#define NWIN 4096
#define WPH 8  // windows per half-block; block covers 16; grid = 256 = 1 block/CU

// ---------------------------------------------------------------------------
// Weight pre-convert: f32 -> f16 into workspace (wq 49152 + wp 16384 elems).
// ---------------------------------------------------------------------------
__global__ void cvt_weights(const float* __restrict__ wq,
                            const float* __restrict__ wp,
                            f16* __restrict__ o) {
    int i = blockIdx.x * blockDim.x + threadIdx.x;
    if (i < 49152) o[i] = (f16)wq[i];
    if (i < 16384) o[49152 + i] = (f16)wp[i];
}

__device__ inline f16x8 cvt8(const float* p) {
    float4 u0 = *(const float4*)p;
    float4 u1 = *(const float4*)(p + 4);
    f16x8 t;
    t[0] = (f16)u0.x; t[1] = (f16)u0.y; t[2] = (f16)u0.z; t[3] = (f16)u0.w;
    t[4] = (f16)u1.x; t[5] = (f16)u1.y; t[6] = (f16)u1.z; t[7] = (f16)u1.w;
    return t;
}

// ---------------------------------------------------------------------------
// Fully fused kernel: 256 blocks x 1024 threads (16 waves = 2 independent
// 8-wave HALVES, each running the verified r16 pipeline on its own window
// stream). Rationale: 512-thr blocks never co-reside (r9-r11) -> 8 waves/CU
// was the TLP ceiling; a 1024-thr workgroup forces 16 waves resident
// (4/SIMD). Block-wide barriers align the halves at identical cadence.
// Phase B processes heads SEQUENTIALLY (P scratch 2KB/wave) to fit LDS:
// 25.6 + 32*3 + 32 = 153KB <= 160KB. Phase bodies = r16 (verified).
// ---------------------------------------------------------------------------
__global__ __launch_bounds__(1024, 1)
void fused_all(const float* __restrict__ x, const float* __restrict__ mask,
               const f16* __restrict__ wq_h, const f16* __restrict__ wp_h,
               const float* __restrict__ bias, float* __restrict__ out) {
    __shared__ f16 xb[2][50 * 128];    // per-half x stage (25.6KB)
    __shared__ f16 qlds[2][64 * 128];  // per-half Q/att (32KB)
    __shared__ f16 klds[2][64 * 128];  // per-half K (32KB)
    __shared__ f16 vlds[2][128 * 64];  // per-half V^T (32KB)
    __shared__ f16 scr[16][1024];      // per-wave P scratch, ONE head (32KB)

    const int tid = threadIdx.x;
    const int wave = tid >> 6;        // 0..15
    const int half = wave >> 3;       // 0/1: independent pipeline
    const int hw = wave & 7;          // wave-in-half
    const int ltid = tid & 511;       // thread-in-half
    const int lane = tid & 63;
    const int lg = lane >> 4;
    const int lr = lane & 15;
    const int w0 = blockIdx.x * (2 * WPH);

    // attention role within half: hw = (M-tile amt, head-pair ahh)
    const int amt = hw & 3;
    const int ahh = hw >> 2;
    const int ar0 = amt * 16;

    f16* ps = scr[wave];  // P tile for the current head (2KB)

    // ---- persistent register weights (per-half copies, L2-hot) ----
    f16x8 bw[3][4];  // qkv ct = {hw, hw+8, hw+16}
#pragma unroll
    for (int j = 0; j < 3; ++j)
#pragma unroll
        for (int kc = 0; kc < 4; ++kc)
            bw[j][kc] = *(const f16x8*)&wq_h[((hw + 8 * j) * 16 + lr) * 128 + kc * 32 + 8 * lg];
    f16x8 wpr[4];  // proj ct = hw
#pragma unroll
    for (int kc = 0; kc < 4; ++kc)
        wpr[kc] = *(const f16x8*)&wp_h[(hw * 16 + lr) * 128 + kc * 32 + 8 * lg];
    const float4 bcv = *(const float4*)&bias[hw * 16 + 4 * lg];

    // stage rows 0..48 of window w into xb[half] (1568 float4 granules)
    auto stage = [&](int w) {
        const float* xw = x + (size_t)w * (49 * 128);
        for (int i = ltid; i < 1568; i += 512) {
            const int row = i >> 5;
            const int c4 = (i & 31) << 2;
            float4 v = ((const float4*)xw)[i];
            f16x4 t;
            t[0] = (f16)v.x; t[1] = (f16)v.y; t[2] = (f16)v.z; t[3] = (f16)v.w;
            *(f16x4*)&xb[half][row * 128 + (c4 ^ ((row & 7) << 3))] = t;
        }
    };

    stage(w0 + half);
    __syncthreads();

    const float sc = 0.17677669529663687f;  // 32^-0.5

    for (int wi = 0; wi < WPH; ++wi) {
        const int w = w0 + 2 * wi + half;

        // mask prefetch, S^T layout: lane needs mask[q=ar0+lr][k=4lg+reg+16nt]
        const float* mw = mask + (size_t)(w & 63) * (49 * 49);
        const int qrow = ar0 + lr;
        float mv[4][4];
#pragma unroll
        for (int reg = 0; reg < 4; ++reg) {
#pragma unroll
            for (int nt = 0; nt < 4; ++nt) {
                const int k = 4 * lg + reg + 16 * nt;
                mv[reg][nt] = (qrow < 49 && k < 49) ? mw[qrow * 49 + k] : 0.f;
            }
        }

        // ========== Phase A: QKV -> LDS (swapped MFMA, vector stores) ======
        f16* ql = qlds[half];
        f16* kl = klds[half];
        f16* vl = vlds[half];
#pragma unroll
        for (int mt = 0; mt < 4; ++mt) {
            const int nb = mt * 16;
            const int xrow = nb + lr;
            f16x8 a[4];
            if (xrow < 49) {
#pragma unroll
                for (int kc = 0; kc < 4; ++kc)
                    a[kc] = *(const f16x8*)&xb[half][xrow * 128 + ((kc * 32 + 8 * lg) ^ ((xrow & 7) << 3))];
            } else {
                f16x8 z = {0, 0, 0, 0, 0, 0, 0, 0};
#pragma unroll
                for (int kc = 0; kc < 4; ++kc) a[kc] = z;
            }

            // Q,K swapped -> lane holds 4 consecutive chans of token lr
#pragma unroll
            for (int j = 0; j < 2; ++j) {
                __builtin_amdgcn_s_setprio(1);
                f32x4 acc = {0.f, 0.f, 0.f, 0.f};
#pragma unroll
                for (int kc = 0; kc < 4; ++kc) acc = MFMA16(bw[j][kc], a[kc], acc);
                __builtin_amdgcn_s_setprio(0);

                const int n = nb + lr;
                const int cb = hw * 16 + 4 * lg;
                f16x4 t;
#pragma unroll
                for (int reg = 0; reg < 4; ++reg) t[reg] = (f16)acc[reg];
                f16* dst = (j == 0) ? ql : kl;
                *(f16x4*)&dst[n * 128 + (cb ^ ((n & 7) << 3))] = t;
            }
            // V normal -> lane holds 4 consecutive tokens of chan lr
            {
                __builtin_amdgcn_s_setprio(1);
                f32x4 acc = {0.f, 0.f, 0.f, 0.f};
#pragma unroll
                for (int kc = 0; kc < 4; ++kc) acc = MFMA16(a[kc], bw[2][kc], acc);
                __builtin_amdgcn_s_setprio(0);

                const int c = hw * 16 + lr;
                f16x4 t;
#pragma unroll
                for (int reg = 0; reg < 4; ++reg) t[reg] = (f16)acc[reg];
                *(f16x4*)&vl[c * 64 + ((nb + 4 * lg) ^ ((c & 7) << 3))] = t;
            }
        }
        __syncthreads();  // bar1: Q/K/V visible; xb consumed

        // restage next window for this half (latency hides under B/C)
        if (wi + 1 < WPH) stage(w + 2);

        // ====== Phase B: attention, heads SEQUENTIAL, swapped QK^T ========
        f32x4 o00, o01, o10, o11;
#pragma unroll
        for (int hi = 0; hi < 2; ++hi) {
            const int h = 2 * ahh + hi;
            f16x8 aq = *(const f16x8*)&ql[qrow * 128 + ((h * 32 + 8 * lg) ^ ((qrow & 7) << 3))];

            // S^T = mfma(K, Q): lane holds S[k=4lg+reg+16nt][q=lr]
            f32x4 s[4];
            __builtin_amdgcn_s_setprio(1);
#pragma unroll
            for (int nt = 0; nt < 4; ++nt) {
                const int krow = nt * 16 + lr;
                f16x8 bk = *(const f16x8*)&kl[krow * 128 + ((h * 32 + 8 * lg) ^ ((krow & 7) << 3))];
                f32x4 z = {0.f, 0.f, 0.f, 0.f};
                s[nt] = MFMA16(bk, aq, z);
            }
            __builtin_amdgcn_s_setprio(0);

            // exp + in-lane partial sums + vector P stores (row q=lr)
            float sum = 0.f;
#pragma unroll
            for (int nt = 0; nt < 4; ++nt) {
                f16x4 pt;
#pragma unroll
                for (int reg = 0; reg < 4; ++reg) {
                    const int k = 4 * lg + reg + 16 * nt;
                    float e = (k < 49) ? __expf(s[nt][reg] * sc + mv[reg][nt]) : 0.f;
                    sum += e;
                    pt[reg] = (f16)e;
                }
                const int off = lr * 64 + ((4 * lg + 16 * nt) ^ ((lr & 7) << 3));
                *(f16x4*)&ps[off] = pt;
            }
            sum += __shfl_xor(sum, 16, 64);
            sum += __shfl_xor(sum, 32, 64);
            const float inv = __fdividef(1.f, sum);

            // V fragments under the P-write lgkm shadow
            f16x8 bv[2][2];
#pragma unroll
            for (int nt = 0; nt < 2; ++nt)
#pragma unroll
                for (int kc = 0; kc < 2; ++kc) {
                    const int vr = h * 32 + nt * 16 + lr;
                    bv[nt][kc] = *(const f16x8*)&vl[vr * 64 + ((kc * 32 + 8 * lg) ^ ((vr & 7) << 3))];
                }

            f16x8 ap[2];
#pragma unroll
            for (int kc = 0; kc < 2; ++kc) {
                const int off = lr * 64 + ((kc * 32 + 8 * lg) ^ ((lr & 7) << 3));
                ap[kc] = *(const f16x8*)&ps[off];
            }
            f32x4 oa = {0.f, 0.f, 0.f, 0.f};
            f32x4 ob_ = {0.f, 0.f, 0.f, 0.f};
            __builtin_amdgcn_s_setprio(1);
#pragma unroll
            for (int kc = 0; kc < 2; ++kc) {
                oa = MFMA16(bv[0][kc], ap[kc], oa);
                ob_ = MFMA16(bv[1][kc], ap[kc], ob_);
            }
            __builtin_amdgcn_s_setprio(0);

#pragma unroll
            for (int reg = 0; reg < 4; ++reg) {
                oa[reg] *= inv;
                ob_[reg] *= inv;
            }
            if (hi == 0) {
                o00 = oa;
                o01 = ob_;
            } else {
                o10 = oa;
                o11 = ob_;
            }
        }

        // att^T -> qlds[half]: 4 consecutive chans per lane -> f16x4 stores
        {
            const int h0 = 2 * ahh;
            const int h1 = 2 * ahh + 1;
            const int n = ar0 + lr;
            const int s = (n & 7) << 3;
            f16x4 t;
#pragma unroll
            for (int reg = 0; reg < 4; ++reg) t[reg] = (f16)o00[reg];
            *(f16x4*)&ql[n * 128 + ((h0 * 32 + 4 * lg) ^ s)] = t;
#pragma unroll
            for (int reg = 0; reg < 4; ++reg) t[reg] = (f16)o01[reg];
            *(f16x4*)&ql[n * 128 + ((h0 * 32 + 16 + 4 * lg) ^ s)] = t;
#pragma unroll
            for (int reg = 0; reg < 4; ++reg) t[reg] = (f16)o10[reg];
            *(f16x4*)&ql[n * 128 + ((h1 * 32 + 4 * lg) ^ s)] = t;
#pragma unroll
            for (int reg = 0; reg < 4; ++reg) t[reg] = (f16)o11[reg];
            *(f16x4*)&ql[n * 128 + ((h1 * 32 + 16 + 4 * lg) ^ s)] = t;
        }
        __syncthreads();  // bar2: att complete

        // ===== Phase C: out projection SWAPPED -> float4 global stores =====
        float* ob = out + (size_t)w * (49 * 128);
#pragma unroll
        for (int mt = 0; mt < 4; ++mt) {
            const int prow = mt * 16 + lr;
            f16x8 aa[4];
#pragma unroll
            for (int kc = 0; kc < 4; ++kc)
                aa[kc] = *(const f16x8*)&ql[prow * 128 + ((kc * 32 + 8 * lg) ^ ((prow & 7) << 3))];
            __builtin_amdgcn_s_setprio(1);
            f32x4 acc = {0.f, 0.f, 0.f, 0.f};
#pragma unroll
            for (int kc = 0; kc < 4; ++kc) acc = MFMA16(wpr[kc], aa[kc], acc);
            __builtin_amdgcn_s_setprio(0);

            if (prow < 49) {
                float4 o;
                o.x = acc[0] + bcv.x;
                o.y = acc[1] + bcv.y;
                o.z = acc[2] + bcv.z;
                o.w = acc[3] + bcv.w;
                *(float4*)&ob[prow * 128 + hw * 16 + 4 * lg] = o;
            }
        }
        __syncthreads();  // bar3: q/k/v free for next A; xb restage landed
    }
}

// ---------------------------------------------------------------------------
// Fallback: fused per-window kernel (no workspace needed).
// ---------------------------------------------------------------------------
template <bool WB>
__global__ __launch_bounds__(256, 4)
void fused_wattn(const float* __restrict__ x, const float* __restrict__ mask,
                 const float* __restrict__ wq_f, const float* __restrict__ wp_f,
                 const f16* __restrict__ wq_h, const f16* __restrict__ wp_h,
                 const float* __restrict__ bias, float* __restrict__ out) {
    __shared__ f16 ks[64 * 128];
    __shared__ f16 vt[128 * 64];
    __shared__ f16 scr[4][1024];

    const int b = blockIdx.x;
    const int wid = b & 63;
    const int tid = threadIdx.x;
    const int wave = tid >> 6;
    const int lane = tid & 63;
    const int lg = lane >> 4;
    const int lr = lane & 15;
    const int r0 = wave * 16;
    f16* ps = scr[wave];

    f16x8 a[4];
    {
        const int xrow = r0 + lr;
        if (xrow < 49) {
            const float* xp = x + ((size_t)b * 49 + xrow) * 128 + 8 * lg;
#pragma unroll
            for (int kc = 0; kc < 4; ++kc) a[kc] = cvt8(xp + kc * 32);
        } else {
            f16x8 z = {0, 0, 0, 0, 0, 0, 0, 0};
#pragma unroll
            for (int kc = 0; kc < 4; ++kc) a[kc] = z;
        }
    }

    float mv[4][4];
#pragma unroll
    for (int reg = 0; reg < 4; ++reg) {
        const int n = r0 + 4 * lg + reg;
#pragma unroll
        for (int nt = 0; nt < 4; ++nt) {
            const int col = nt * 16 + lr;
            mv[reg][nt] = (n < 49 && col < 49) ? mask[((size_t)wid * 49 + n) * 49 + col] : 0.f;
        }
    }

    f16x4 qd[8];
#pragma unroll
    for (int ct = 0; ct < 24; ++ct) {
        const int wrow = ct * 16 + lr;
        f16x8 bw[4];
        if (WB) {
#pragma unroll
            for (int kc = 0; kc < 4; ++kc)
                bw[kc] = *(const f16x8*)&wq_h[wrow * 128 + kc * 32 + 8 * lg];
        } else {
#pragma unroll
            for (int kc = 0; kc < 4; ++kc)
                bw[kc] = cvt8(&wq_f[wrow * 128 + kc * 32 + 8 * lg]);
        }
        f32x4 acc = {0.f, 0.f, 0.f, 0.f};
#pragma unroll
        for (int kc = 0; kc < 4; ++kc) acc = MFMA16(a[kc], bw[kc], acc);

        if (ct < 8) {
            f16x4 q;
#pragma unroll
            for (int reg = 0; reg < 4; ++reg) q[reg] = (f16)acc[reg];
            qd[ct] = q;
        } else if (ct < 16) {
#pragma unroll
            for (int reg = 0; reg < 4; ++reg) {
                const int n = r0 + 4 * lg + reg;
                const int c = wrow - 128;
                ks[n * 128 + (c ^ ((n & 7) << 3))] = (f16)acc[reg];
            }
        } else {
#pragma unroll
            for (int reg = 0; reg < 4; ++reg) {
                const int n = r0 + 4 * lg + reg;
                const int dch = wrow - 256;
                vt[dch * 64 + (n ^ ((dch & 7) << 3))] = (f16)acc[reg];
            }
        }
    }
    __syncthreads();

    const float sc = 0.17677669529663687f;
    f32x4 oacc[4][2];

#pragma unroll
    for (int h = 0; h < 4; ++h) {
#pragma unroll
        for (int c2 = 0; c2 < 2; ++c2)
#pragma unroll
            for (int reg = 0; reg < 4; ++reg) {
                const int row = 4 * lg + reg;
                const int col = c2 * 16 + lr;
                ps[row * 32 + (col ^ ((row & 3) << 3))] = qd[2 * h + c2][reg];
            }
        f16x8 aq = *(const f16x8*)&ps[lr * 32 + ((8 * lg) ^ ((lr & 3) << 3))];

        f32x4 s[4];
#pragma unroll
        for (int nt = 0; nt < 4; ++nt) {
            const int krow = nt * 16 + lr;
            f16x8 bk = *(const f16x8*)&ks[krow * 128 + ((h * 32 + 8 * lg) ^ ((krow & 7) << 3))];
            f32x4 z = {0.f, 0.f, 0.f, 0.f};
            s[nt] = MFMA16(aq, bk, z);
        }

#pragma unroll
        for (int reg = 0; reg < 4; ++reg) {
            float vals[4];
            float sum = 0.f;
#pragma unroll
            for (int nt = 0; nt < 4; ++nt) {
                const int col = nt * 16 + lr;
                float e = (col < 49) ? __expf(s[nt][reg] * sc + mv[reg][nt]) : 0.f;
                vals[nt] = e;
                sum += e;
            }
            for (int d = 1; d < 16; d <<= 1) sum += __shfl_xor(sum, d, 64);
            const float inv = __fdividef(1.f, sum);
            const int row = 4 * lg + reg;
#pragma unroll
            for (int nt = 0; nt < 4; ++nt) {
                const int col = nt * 16 + lr;
                ps[row * 64 + (col ^ ((row & 7) << 3))] = (f16)(vals[nt] * inv);
            }
        }

        f16x8 ap[2];
#pragma unroll
        for (int kc = 0; kc < 2; ++kc)
            ap[kc] = *(const f16x8*)&ps[lr * 64 + ((kc * 32 + 8 * lg) ^ ((lr & 7) << 3))];
#pragma unroll
        for (int nt = 0; nt < 2; ++nt) {
            const int vrow = h * 32 + nt * 16 + lr;
            f32x4 acc = {0.f, 0.f, 0.f, 0.f};
#pragma unroll
            for (int kc = 0; kc < 2; ++kc) {
                f16x8 bv = *(const f16x8*)&vt[vrow * 64 + ((kc * 32 + 8 * lg) ^ ((vrow & 7) << 3))];
                acc = MFMA16(ap[kc], bv, acc);
            }
            oacc[h][nt] = acc;
        }
    }

    f16x8 aa[4];
#pragma unroll
    for (int pass = 0; pass < 2; ++pass) {
#pragma unroll
        for (int h2 = 0; h2 < 2; ++h2)
#pragma unroll
            for (int nt = 0; nt < 2; ++nt)
#pragma unroll
                for (int reg = 0; reg < 4; ++reg) {
                    const int row = 4 * lg + reg;
                    const int col = h2 * 32 + nt * 16 + lr;
                    ps[row * 64 + (col ^ ((row & 7) << 3))] = (f16)oacc[pass * 2 + h2][nt][reg];
                }
#pragma unroll
        for (int kcg = 0; kcg < 2; ++kcg)
            aa[pass * 2 + kcg] = *(const f16x8*)&ps[lr * 64 + ((kcg * 32 + 8 * lg) ^ ((lr & 7) << 3))];
    }

    float* ob = out + (size_t)b * (49 * 128);
#pragma unroll
    for (int ct = 0; ct < 8; ++ct) {
        const int wrow = ct * 16 + lr;
        f16x8 bw[4];
        if (WB) {
#pragma unroll
            for (int kc = 0; kc < 4; ++kc)
                bw[kc] = *(const f16x8*)&wp_h[wrow * 128 + kc * 32 + 8 * lg];
        } else {
#pragma unroll
            for (int kc = 0; kc < 4; ++kc)
                bw[kc] = cvt8(&wp_f[wrow * 128 + kc * 32 + 8 * lg]);
        }
        f32x4 acc = {0.f, 0.f, 0.f, 0.f};
#pragma unroll
        for (int kc = 0; kc < 4; ++kc) acc = MFMA16(aa[kc], bw[kc], acc);

        const float bc = bias[wrow];
#pragma unroll
        for (int reg = 0; reg < 4; ++reg) {
            const int n = r0 + 4 * lg + reg;
            if (n < 49) ob[n * 128 + ct * 16 + lr] = acc[reg] + bc;
        }
    }
}

extern "C" void kernel_launch(void* const* d_in, const int* in_sizes, int n_in,
                              void* d_out, int out_size, void* d_ws, size_t ws_size,
                              hipStream_t stream) {
    const float* x = (const float*)d_in[0];
    const float* mask = (const float*)d_in[1];
    const float* wq = (const float*)d_in[2];
    const float* wp = (const float*)d_in[3];
    const float* bp = (const float*)d_in[4];
    float* out = (float*)d_out;

    const size_t need_wb = (size_t)(49152 + 16384) * sizeof(f16);

    if (ws_size >= need_wb && d_ws != nullptr) {
        f16* wsh = (f16*)d_ws;
        cvt_weights<<<192, 256, 0, stream>>>(wq, wp, wsh);
        fused_all<<<NWIN / (2 * WPH), 1024, 0, stream>>>(x, mask, wsh, wsh + 49152, bp, out);
    } else {
        fused_wattn<false><<<4096, 256, 0, stream>>>(x, mask, wq, wp, nullptr, nullptr, bp, out);
    }
}

// Round 18
// 90.899 us; speedup vs baseline: 2.3967x; 2.3967x over previous
//
#include <hip/hip_runtime.h>
#include <hip/hip_bf16.h>

typedef _Float16 f16;
typedef __attribute__((ext_vector_type(8))) _Float16 f16x8;
typedef __attribute__((ext_vector_type(4))) _Float16 f16x4;
typedef __attribute__((ext_vector_type(4))) float f32x4;

#define MFMA16(a, b, c) __builtin_amdgcn_mfma_f32_16x16x32_f16((a), (b), (c), 0, 0, 0)

#define NWIN 4096
#define WPB 16  // windows per block (8 pairs); grid = 256 = 1 block/CU

// ---------------------------------------------------------------------------
// Weight pre-convert: f32 -> f16 into workspace (wq 49152 + wp 16384 elems).
// ---------------------------------------------------------------------------
__global__ void cvt_weights(const float* __restrict__ wq,
                            const float* __restrict__ wp,
                            f16* __restrict__ o) {
    int i = blockIdx.x * blockDim.x + threadIdx.x;
    if (i < 49152) o[i] = (f16)wq[i];
    if (i < 16384) o[49152 + i] = (f16)wp[i];
}

__device__ inline f16x8 cvt8(const float* p) {
    float4 u0 = *(const float4*)p;
    float4 u1 = *(const float4*)(p + 4);
    f16x8 t;
    t[0] = (f16)u0.x; t[1] = (f16)u0.y; t[2] = (f16)u0.z; t[3] = (f16)u0.w;
    t[4] = (f16)u1.x; t[5] = (f16)u1.y; t[6] = (f16)u1.z; t[7] = (f16)u1.w;
    return t;
}

// ---------------------------------------------------------------------------
// Fully fused kernel: 256 blocks x 512 threads (8 waves), 16 windows each,
// processed in PAIRS at phase granularity:
//   A(w0);A(w1) bar  B(w0);B(w1) bar  C(w0);C(w1) bar
// Each inter-barrier region holds TWO independent dep chains -> in-wave ILP
// (TLP is pinned at 2 waves/SIMD: 512-thr blocks never co-reside r9-r11;
// 1024-thr blocks trigger a 64-VGPR cap r17). Barriers 2/window -> 1.5.
// Register discipline (r13 spilled at this): heads SEQUENTIAL in B
// (r17-verified math), per-window 1KB P slots (no false LDS serialization),
// mv loaded lazily inside B(ws). r16 verified phase bodies throughout.
// LDS 137.6KB; VGPR base 88, cap 128. Spill canary: FETCH_SIZE.
// ---------------------------------------------------------------------------
__global__ __launch_bounds__(512, 1)
void fused_all(const float* __restrict__ x, const float* __restrict__ mask,
               const f16* __restrict__ wq_h, const f16* __restrict__ wp_h,
               const float* __restrict__ bias, float* __restrict__ out) {
    __shared__ f16 xb[2][50 * 128];    // per-pair-window x stage (25.6KB)
    __shared__ f16 qlds[2][64 * 128];  // per-window Q/att (32KB)
    __shared__ f16 klds[2][64 * 128];  // per-window K (32KB)
    __shared__ f16 vlds[2][128 * 64];  // per-window V^T (32KB)
    __shared__ f16 scr[8][2048];       // per-wave: 2 x 1KB P slots (16KB)

    const int tid = threadIdx.x;
    const int wave = tid >> 6;
    const int lane = tid & 63;
    const int lg = lane >> 4;
    const int lr = lane & 15;
    const int w0 = blockIdx.x * WPB;

    // attention role: wave = (M-tile amt, head-pair ahh -> heads 2ahh,2ahh+1)
    const int amt = wave & 3;
    const int ahh = wave >> 2;
    const int ar0 = amt * 16;
    const int qrow = ar0 + lr;

    // ---- persistent register weights ----
    f16x8 bw[3][4];  // qkv ct = {wave, wave+8, wave+16}
#pragma unroll
    for (int j = 0; j < 3; ++j)
#pragma unroll
        for (int kc = 0; kc < 4; ++kc)
            bw[j][kc] = *(const f16x8*)&wq_h[((wave + 8 * j) * 16 + lr) * 128 + kc * 32 + 8 * lg];
    f16x8 wpr[4];  // proj ct = wave
#pragma unroll
    for (int kc = 0; kc < 4; ++kc)
        wpr[kc] = *(const f16x8*)&wp_h[(wave * 16 + lr) * 128 + kc * 32 + 8 * lg];
    const float4 bcv = *(const float4*)&bias[wave * 16 + 4 * lg];

    // stage rows 0..48 of window w into xb[p] (1568 float4 granules)
    auto stage = [&](int w, int p) {
        const float* xw = x + (size_t)w * (49 * 128);
        for (int i = tid; i < 1568; i += 512) {
            const int row = i >> 5;
            const int c4 = (i & 31) << 2;
            float4 v = ((const float4*)xw)[i];
            f16x4 t;
            t[0] = (f16)v.x; t[1] = (f16)v.y; t[2] = (f16)v.z; t[3] = (f16)v.w;
            *(f16x4*)&xb[p][row * 128 + (c4 ^ ((row & 7) << 3))] = t;
        }
    };

    stage(w0, 0);
    stage(w0 + 1, 1);
    __syncthreads();

    const float sc = 0.17677669529663687f;  // 32^-0.5

    for (int pi = 0; pi < WPB / 2; ++pi) {
        const int wA = w0 + 2 * pi;

        // ===== Phase A, both windows (r16 body: swapped MFMA, f16x4 stores)
#pragma unroll
        for (int ws = 0; ws < 2; ++ws) {
            f16* ql = qlds[ws];
            f16* kl = klds[ws];
            f16* vl = vlds[ws];
#pragma unroll
            for (int mt = 0; mt < 4; ++mt) {
                const int nb = mt * 16;
                const int xrow = nb + lr;
                f16x8 a[4];
                if (xrow < 49) {
#pragma unroll
                    for (int kc = 0; kc < 4; ++kc)
                        a[kc] = *(const f16x8*)&xb[ws][xrow * 128 + ((kc * 32 + 8 * lg) ^ ((xrow & 7) << 3))];
                } else {
                    f16x8 z = {0, 0, 0, 0, 0, 0, 0, 0};
#pragma unroll
                    for (int kc = 0; kc < 4; ++kc) a[kc] = z;
                }

#pragma unroll
                for (int j = 0; j < 2; ++j) {
                    __builtin_amdgcn_s_setprio(1);
                    f32x4 acc = {0.f, 0.f, 0.f, 0.f};
#pragma unroll
                    for (int kc = 0; kc < 4; ++kc) acc = MFMA16(bw[j][kc], a[kc], acc);
                    __builtin_amdgcn_s_setprio(0);

                    const int n = nb + lr;
                    const int cb = wave * 16 + 4 * lg;
                    f16x4 t;
#pragma unroll
                    for (int reg = 0; reg < 4; ++reg) t[reg] = (f16)acc[reg];
                    f16* dst = (j == 0) ? ql : kl;
                    *(f16x4*)&dst[n * 128 + (cb ^ ((n & 7) << 3))] = t;
                }
                {
                    __builtin_amdgcn_s_setprio(1);
                    f32x4 acc = {0.f, 0.f, 0.f, 0.f};
#pragma unroll
                    for (int kc = 0; kc < 4; ++kc) acc = MFMA16(a[kc], bw[2][kc], acc);
                    __builtin_amdgcn_s_setprio(0);

                    const int c = wave * 16 + lr;
                    f16x4 t;
#pragma unroll
                    for (int reg = 0; reg < 4; ++reg) t[reg] = (f16)acc[reg];
                    *(f16x4*)&vl[c * 64 + ((nb + 4 * lg) ^ ((c & 7) << 3))] = t;
                }
            }
        }
        __syncthreads();  // bar1: Q/K/V (both windows) visible; xb consumed

        // restage next pair (latency hides under B/C)
        if (pi + 1 < WPB / 2) {
            stage(wA + 2, 0);
            stage(wA + 3, 1);
        }

        // ===== Phase B, both windows (heads sequential, swapped QK^T) =====
#pragma unroll
        for (int ws = 0; ws < 2; ++ws) {
            const int w = wA + ws;
            f16* ql = qlds[ws];
            f16* kl = klds[ws];
            f16* vl = vlds[ws];
            f16* psw = scr[wave] + (ws << 10);

            const float* mw = mask + (size_t)(w & 63) * (49 * 49);
            float mv[4][4];
#pragma unroll
            for (int reg = 0; reg < 4; ++reg) {
#pragma unroll
                for (int nt = 0; nt < 4; ++nt) {
                    const int k = 4 * lg + reg + 16 * nt;
                    mv[reg][nt] = (qrow < 49 && k < 49) ? mw[qrow * 49 + k] : 0.f;
                }
            }

            f32x4 o00, o01, o10, o11;
#pragma unroll
            for (int hi = 0; hi < 2; ++hi) {
                const int h = 2 * ahh + hi;
                f16x8 aq = *(const f16x8*)&ql[qrow * 128 + ((h * 32 + 8 * lg) ^ ((qrow & 7) << 3))];

                f32x4 s[4];
                __builtin_amdgcn_s_setprio(1);
#pragma unroll
                for (int nt = 0; nt < 4; ++nt) {
                    const int krow = nt * 16 + lr;
                    f16x8 bk = *(const f16x8*)&kl[krow * 128 + ((h * 32 + 8 * lg) ^ ((krow & 7) << 3))];
                    f32x4 z = {0.f, 0.f, 0.f, 0.f};
                    s[nt] = MFMA16(bk, aq, z);
                }
                __builtin_amdgcn_s_setprio(0);

                float sum = 0.f;
#pragma unroll
                for (int nt = 0; nt < 4; ++nt) {
                    f16x4 pt;
#pragma unroll
                    for (int reg = 0; reg < 4; ++reg) {
                        const int k = 4 * lg + reg + 16 * nt;
                        float e = (k < 49) ? __expf(s[nt][reg] * sc + mv[reg][nt]) : 0.f;
                        sum += e;
                        pt[reg] = (f16)e;
                    }
                    const int off = lr * 64 + ((4 * lg + 16 * nt) ^ ((lr & 7) << 3));
                    *(f16x4*)&psw[off] = pt;
                }
                sum += __shfl_xor(sum, 16, 64);
                sum += __shfl_xor(sum, 32, 64);
                const float inv = __fdividef(1.f, sum);

                f16x8 bv[2][2];
#pragma unroll
                for (int nt = 0; nt < 2; ++nt)
#pragma unroll
                    for (int kc = 0; kc < 2; ++kc) {
                        const int vr = h * 32 + nt * 16 + lr;
                        bv[nt][kc] = *(const f16x8*)&vl[vr * 64 + ((kc * 32 + 8 * lg) ^ ((vr & 7) << 3))];
                    }

                f16x8 ap[2];
#pragma unroll
                for (int kc = 0; kc < 2; ++kc) {
                    const int off = lr * 64 + ((kc * 32 + 8 * lg) ^ ((lr & 7) << 3));
                    ap[kc] = *(const f16x8*)&psw[off];
                }
                f32x4 oa = {0.f, 0.f, 0.f, 0.f};
                f32x4 ob_ = {0.f, 0.f, 0.f, 0.f};
                __builtin_amdgcn_s_setprio(1);
#pragma unroll
                for (int kc = 0; kc < 2; ++kc) {
                    oa = MFMA16(bv[0][kc], ap[kc], oa);
                    ob_ = MFMA16(bv[1][kc], ap[kc], ob_);
                }
                __builtin_amdgcn_s_setprio(0);

#pragma unroll
                for (int reg = 0; reg < 4; ++reg) {
                    oa[reg] *= inv;
                    ob_[reg] *= inv;
                }
                if (hi == 0) {
                    o00 = oa;
                    o01 = ob_;
                } else {
                    o10 = oa;
                    o11 = ob_;
                }
            }

            // att^T -> qlds[ws] (wave overwrites exactly its Q region)
            {
                const int h0 = 2 * ahh;
                const int h1 = 2 * ahh + 1;
                const int n = ar0 + lr;
                const int s = (n & 7) << 3;
                f16x4 t;
#pragma unroll
                for (int reg = 0; reg < 4; ++reg) t[reg] = (f16)o00[reg];
                *(f16x4*)&ql[n * 128 + ((h0 * 32 + 4 * lg) ^ s)] = t;
#pragma unroll
                for (int reg = 0; reg < 4; ++reg) t[reg] = (f16)o01[reg];
                *(f16x4*)&ql[n * 128 + ((h0 * 32 + 16 + 4 * lg) ^ s)] = t;
#pragma unroll
                for (int reg = 0; reg < 4; ++reg) t[reg] = (f16)o10[reg];
                *(f16x4*)&ql[n * 128 + ((h1 * 32 + 4 * lg) ^ s)] = t;
#pragma unroll
                for (int reg = 0; reg < 4; ++reg) t[reg] = (f16)o11[reg];
                *(f16x4*)&ql[n * 128 + ((h1 * 32 + 16 + 4 * lg) ^ s)] = t;
            }
        }
        __syncthreads();  // bar2: att (both windows) complete

        // ===== Phase C, both windows (swapped proj -> float4 stores) ======
#pragma unroll
        for (int ws = 0; ws < 2; ++ws) {
            const f16* ql = qlds[ws];
            float* ob = out + (size_t)(wA + ws) * (49 * 128);
#pragma unroll
            for (int mt = 0; mt < 4; ++mt) {
                const int prow = mt * 16 + lr;
                f16x8 aa[4];
#pragma unroll
                for (int kc = 0; kc < 4; ++kc)
                    aa[kc] = *(const f16x8*)&ql[prow * 128 + ((kc * 32 + 8 * lg) ^ ((prow & 7) << 3))];
                __builtin_amdgcn_s_setprio(1);
                f32x4 acc = {0.f, 0.f, 0.f, 0.f};
#pragma unroll
                for (int kc = 0; kc < 4; ++kc) acc = MFMA16(wpr[kc], aa[kc], acc);
                __builtin_amdgcn_s_setprio(0);

                if (prow < 49) {
                    float4 o;
                    o.x = acc[0] + bcv.x;
                    o.y = acc[1] + bcv.y;
                    o.z = acc[2] + bcv.z;
                    o.w = acc[3] + bcv.w;
                    *(float4*)&ob[prow * 128 + wave * 16 + 4 * lg] = o;
                }
            }
        }
        __syncthreads();  // bar3: q/k/v free for next pair's phase A
    }
}

// ---------------------------------------------------------------------------
// Fallback: fused per-window kernel (no workspace needed).
// ---------------------------------------------------------------------------
template <bool WB>
__global__ __launch_bounds__(256, 4)
void fused_wattn(const float* __restrict__ x, const float* __restrict__ mask,
                 const float* __restrict__ wq_f, const float* __restrict__ wp_f,
                 const f16* __restrict__ wq_h, const f16* __restrict__ wp_h,
                 const float* __restrict__ bias, float* __restrict__ out) {
    __shared__ f16 ks[64 * 128];
    __shared__ f16 vt[128 * 64];
    __shared__ f16 scr[4][1024];

    const int b = blockIdx.x;
    const int wid = b & 63;
    const int tid = threadIdx.x;
    const int wave = tid >> 6;
    const int lane = tid & 63;
    const int lg = lane >> 4;
    const int lr = lane & 15;
    const int r0 = wave * 16;
    f16* ps = scr[wave];

    f16x8 a[4];
    {
        const int xrow = r0 + lr;
        if (xrow < 49) {
            const float* xp = x + ((size_t)b * 49 + xrow) * 128 + 8 * lg;
#pragma unroll
            for (int kc = 0; kc < 4; ++kc) a[kc] = cvt8(xp + kc * 32);
        } else {
            f16x8 z = {0, 0, 0, 0, 0, 0, 0, 0};
#pragma unroll
            for (int kc = 0; kc < 4; ++kc) a[kc] = z;
        }
    }

    float mv[4][4];
#pragma unroll
    for (int reg = 0; reg < 4; ++reg) {
        const int n = r0 + 4 * lg + reg;
#pragma unroll
        for (int nt = 0; nt < 4; ++nt) {
            const int col = nt * 16 + lr;
            mv[reg][nt] = (n < 49 && col < 49) ? mask[((size_t)wid * 49 + n) * 49 + col] : 0.f;
        }
    }

    f16x4 qd[8];
#pragma unroll
    for (int ct = 0; ct < 24; ++ct) {
        const int wrow = ct * 16 + lr;
        f16x8 bw[4];
        if (WB) {
#pragma unroll
            for (int kc = 0; kc < 4; ++kc)
                bw[kc] = *(const f16x8*)&wq_h[wrow * 128 + kc * 32 + 8 * lg];
        } else {
#pragma unroll
            for (int kc = 0; kc < 4; ++kc)
                bw[kc] = cvt8(&wq_f[wrow * 128 + kc * 32 + 8 * lg]);
        }
        f32x4 acc = {0.f, 0.f, 0.f, 0.f};
#pragma unroll
        for (int kc = 0; kc < 4; ++kc) acc = MFMA16(a[kc], bw[kc], acc);

        if (ct < 8) {
            f16x4 q;
#pragma unroll
            for (int reg = 0; reg < 4; ++reg) q[reg] = (f16)acc[reg];
            qd[ct] = q;
        } else if (ct < 16) {
#pragma unroll
            for (int reg = 0; reg < 4; ++reg) {
                const int n = r0 + 4 * lg + reg;
                const int c = wrow - 128;
                ks[n * 128 + (c ^ ((n & 7) << 3))] = (f16)acc[reg];
            }
        } else {
#pragma unroll
            for (int reg = 0; reg < 4; ++reg) {
                const int n = r0 + 4 * lg + reg;
                const int dch = wrow - 256;
                vt[dch * 64 + (n ^ ((dch & 7) << 3))] = (f16)acc[reg];
            }
        }
    }
    __syncthreads();

    const float sc = 0.17677669529663687f;
    f32x4 oacc[4][2];

#pragma unroll
    for (int h = 0; h < 4; ++h) {
#pragma unroll
        for (int c2 = 0; c2 < 2; ++c2)
#pragma unroll
            for (int reg = 0; reg < 4; ++reg) {
                const int row = 4 * lg + reg;
                const int col = c2 * 16 + lr;
                ps[row * 32 + (col ^ ((row & 3) << 3))] = qd[2 * h + c2][reg];
            }
        f16x8 aq = *(const f16x8*)&ps[lr * 32 + ((8 * lg) ^ ((lr & 3) << 3))];

        f32x4 s[4];
#pragma unroll
        for (int nt = 0; nt < 4; ++nt) {
            const int krow = nt * 16 + lr;
            f16x8 bk = *(const f16x8*)&ks[krow * 128 + ((h * 32 + 8 * lg) ^ ((krow & 7) << 3))];
            f32x4 z = {0.f, 0.f, 0.f, 0.f};
            s[nt] = MFMA16(aq, bk, z);
        }

#pragma unroll
        for (int reg = 0; reg < 4; ++reg) {
            float vals[4];
            float sum = 0.f;
#pragma unroll
            for (int nt = 0; nt < 4; ++nt) {
                const int col = nt * 16 + lr;
                float e = (col < 49) ? __expf(s[nt][reg] * sc + mv[reg][nt]) : 0.f;
                vals[nt] = e;
                sum += e;
            }
            for (int d = 1; d < 16; d <<= 1) sum += __shfl_xor(sum, d, 64);
            const float inv = __fdividef(1.f, sum);
            const int row = 4 * lg + reg;
#pragma unroll
            for (int nt = 0; nt < 4; ++nt) {
                const int col = nt * 16 + lr;
                ps[row * 64 + (col ^ ((row & 7) << 3))] = (f16)(vals[nt] * inv);
            }
        }

        f16x8 ap[2];
#pragma unroll
        for (int kc = 0; kc < 2; ++kc)
            ap[kc] = *(const f16x8*)&ps[lr * 64 + ((kc * 32 + 8 * lg) ^ ((lr & 7) << 3))];
#pragma unroll
        for (int nt = 0; nt < 2; ++nt) {
            const int vrow = h * 32 + nt * 16 + lr;
            f32x4 acc = {0.f, 0.f, 0.f, 0.f};
#pragma unroll
            for (int kc = 0; kc < 2; ++kc) {
                f16x8 bv = *(const f16x8*)&vt[vrow * 64 + ((kc * 32 + 8 * lg) ^ ((vrow & 7) << 3))];
                acc = MFMA16(ap[kc], bv, acc);
            }
            oacc[h][nt] = acc;
        }
    }

    f16x8 aa[4];
#pragma unroll
    for (int pass = 0; pass < 2; ++pass) {
#pragma unroll
        for (int h2 = 0; h2 < 2; ++h2)
#pragma unroll
            for (int nt = 0; nt < 2; ++nt)
#pragma unroll
                for (int reg = 0; reg < 4; ++reg) {
                    const int row = 4 * lg + reg;
                    const int col = h2 * 32 + nt * 16 + lr;
                    ps[row * 64 + (col ^ ((row & 7) << 3))] = (f16)oacc[pass * 2 + h2][nt][reg];
                }
#pragma unroll
        for (int kcg = 0; kcg < 2; ++kcg)
            aa[pass * 2 + kcg] = *(const f16x8*)&ps[lr * 64 + ((kcg * 32 + 8 * lg) ^ ((lr & 7) << 3))];
    }

    float* ob = out + (size_t)b * (49 * 128);
#pragma unroll
    for (int ct = 0; ct < 8; ++ct) {
        const int wrow = ct * 16 + lr;
        f16x8 bw[4];
        if (WB) {
#pragma unroll
            for (int kc = 0; kc < 4; ++kc)
                bw[kc] = *(const f16x8*)&wp_h[wrow * 128 + kc * 32 + 8 * lg];
        } else {
#pragma unroll
            for (int kc = 0; kc < 4; ++kc)
                bw[kc] = cvt8(&wp_f[wrow * 128 + kc * 32 + 8 * lg]);
        }
        f32x4 acc = {0.f, 0.f, 0.f, 0.f};
#pragma unroll
        for (int kc = 0; kc < 4; ++kc) acc = MFMA16(aa[kc], bw[kc], acc);

        const float bc = bias[wrow];
#pragma unroll
        for (int reg = 0; reg < 4; ++reg) {
            const int n = r0 + 4 * lg + reg;
            if (n < 49) ob[n * 128 + ct * 16 + lr] = acc[reg] + bc;
        }
    }
}

extern "C" void kernel_launch(void* const* d_in, const int* in_sizes, int n_in,
                              void* d_out, int out_size, void* d_ws, size_t ws_size,
                              hipStream_t stream) {
    const float* x = (const float*)d_in[0];
    const float* mask = (const float*)d_in[1];
    const float* wq = (const float*)d_in[2];
    const float* wp = (const float*)d_in[3];
    const float* bp = (const float*)d_in[4];
    float* out = (float*)d_out;

    const size_t need_wb = (size_t)(49152 + 16384) * sizeof(f16);

    if (ws_size >= need_wb && d_ws != nullptr) {
        f16* wsh = (f16*)d_ws;
        cvt_weights<<<192, 256, 0, stream>>>(wq, wp, wsh);
        fused_all<<<NWIN / WPB, 512, 0, stream>>>(x, mask, wsh, wsh + 49152, bp, out);
    } else {
        fused_wattn<false><<<4096, 256, 0, stream>>>(x, mask, wq, wp, nullptr, nullptr, bp, out);
    }
}

// Round 20
// 90.878 us; speedup vs baseline: 2.3972x; 1.0002x over previous
//
#include <hip/hip_runtime.h>
#include <hip/hip_bf16.h>

typedef _Float16 f16;
typedef __attribute__((ext_vector_type(8))) _Float16 f16x8;
typedef __attribute__((ext_vector_type(4))) _Float16 f16x4;
typedef __attribute__((ext_vector_type(4))) float f32x4;

#define MFMA16(a, b, c) __builtin_amdgcn_mfma_f32_16x16x32_f16((a), (b), (c), 0, 0, 0)

#define NWIN 4096
#define WPB 16  // windows per block (8 pairs); grid = 256 = 1 block/CU

// ---------------------------------------------------------------------------
// Weight pre-convert: f32 -> f16 into workspace (wq 49152 + wp 16384 elems).
// ---------------------------------------------------------------------------
__global__ void cvt_weights(const float* __restrict__ wq,
                            const float* __restrict__ wp,
                            f16* __restrict__ o) {
    int i = blockIdx.x * blockDim.x + threadIdx.x;
    if (i < 49152) o[i] = (f16)wq[i];
    if (i < 16384) o[49152 + i] = (f16)wp[i];
}

__device__ inline f16x8 cvt8(const float* p) {
    float4 u0 = *(const float4*)p;
    float4 u1 = *(const float4*)(p + 4);
    f16x8 t;
    t[0] = (f16)u0.x; t[1] = (f16)u0.y; t[2] = (f16)u0.z; t[3] = (f16)u0.w;
    t[4] = (f16)u1.x; t[5] = (f16)u1.y; t[6] = (f16)u1.z; t[7] = (f16)u1.w;
    return t;
}

// ---------------------------------------------------------------------------
// Fully fused kernel: 256 blocks x 512 threads (8 waves), 16 windows each,
// processed in PAIRS at phase granularity (r18, +7us proven) with phase B
// heads RE-FUSED (r16 verified body). P slots (2 x 1024-f16 per wave) are
// SHARED across the window pair — same-wave DS ops execute in order, so
// ws0's PV reads complete before ws1's P writes (r19's per-window slots
// overflowed LDS: 2KB/slot, not 1KB). Mask predicate folded into mv
// (-1e30 for k>=49 -> exp underflow 0; pad q-rows keep 0 so sums > 0).
// LDS 156672B (proven footprint). Spill canary: FETCH_SIZE ~51MB.
// TLP pinned at 2 waves/SIMD (r9-r11 no-coreside, r17 64-VGPR cap).
// ---------------------------------------------------------------------------
__global__ __launch_bounds__(512, 1)
void fused_all(const float* __restrict__ x, const float* __restrict__ mask,
               const f16* __restrict__ wq_h, const f16* __restrict__ wp_h,
               const float* __restrict__ bias, float* __restrict__ out) {
    __shared__ f16 xb[2][50 * 128];    // per-pair-window x stage (25.6KB)
    __shared__ f16 qlds[2][64 * 128];  // per-window Q/att (32KB)
    __shared__ f16 klds[2][64 * 128];  // per-window K (32KB)
    __shared__ f16 vlds[2][128 * 64];  // per-window V^T (32KB)
    __shared__ f16 scr[8][2048];       // per-wave: 2 head P slots, pair-shared (32KB)

    const int tid = threadIdx.x;
    const int wave = tid >> 6;
    const int lane = tid & 63;
    const int lg = lane >> 4;
    const int lr = lane & 15;
    const int w0 = blockIdx.x * WPB;

    // attention role: wave = (M-tile amt, head-pair ahh -> heads 2ahh,2ahh+1)
    const int amt = wave & 3;
    const int ahh = wave >> 2;
    const int ar0 = amt * 16;
    const int qrow = ar0 + lr;

    f16* ps0 = scr[wave];         // P slot head h0 (1024 f16)
    f16* ps1 = scr[wave] + 1024;  // P slot head h1 (1024 f16)

    // ---- persistent register weights ----
    f16x8 bw[3][4];  // qkv ct = {wave, wave+8, wave+16}
#pragma unroll
    for (int j = 0; j < 3; ++j)
#pragma unroll
        for (int kc = 0; kc < 4; ++kc)
            bw[j][kc] = *(const f16x8*)&wq_h[((wave + 8 * j) * 16 + lr) * 128 + kc * 32 + 8 * lg];
    f16x8 wpr[4];  // proj ct = wave
#pragma unroll
    for (int kc = 0; kc < 4; ++kc)
        wpr[kc] = *(const f16x8*)&wp_h[(wave * 16 + lr) * 128 + kc * 32 + 8 * lg];
    const float4 bcv = *(const float4*)&bias[wave * 16 + 4 * lg];

    // stage rows 0..48 of window w into xb[p] (1568 float4 granules)
    auto stage = [&](int w, int p) {
        const float* xw = x + (size_t)w * (49 * 128);
        for (int i = tid; i < 1568; i += 512) {
            const int row = i >> 5;
            const int c4 = (i & 31) << 2;
            float4 v = ((const float4*)xw)[i];
            f16x4 t;
            t[0] = (f16)v.x; t[1] = (f16)v.y; t[2] = (f16)v.z; t[3] = (f16)v.w;
            *(f16x4*)&xb[p][row * 128 + (c4 ^ ((row & 7) << 3))] = t;
        }
    };

    stage(w0, 0);
    stage(w0 + 1, 1);
    __syncthreads();

    const float sc = 0.17677669529663687f;  // 32^-0.5

    for (int pi = 0; pi < WPB / 2; ++pi) {
        const int wA = w0 + 2 * pi;

        // ===== Phase A, both windows (r16 body: swapped MFMA, f16x4 stores)
#pragma unroll
        for (int ws = 0; ws < 2; ++ws) {
            f16* ql = qlds[ws];
            f16* kl = klds[ws];
            f16* vl = vlds[ws];
#pragma unroll
            for (int mt = 0; mt < 4; ++mt) {
                const int nb = mt * 16;
                const int xrow = nb + lr;
                f16x8 a[4];
                if (xrow < 49) {
#pragma unroll
                    for (int kc = 0; kc < 4; ++kc)
                        a[kc] = *(const f16x8*)&xb[ws][xrow * 128 + ((kc * 32 + 8 * lg) ^ ((xrow & 7) << 3))];
                } else {
                    f16x8 z = {0, 0, 0, 0, 0, 0, 0, 0};
#pragma unroll
                    for (int kc = 0; kc < 4; ++kc) a[kc] = z;
                }

#pragma unroll
                for (int j = 0; j < 2; ++j) {
                    __builtin_amdgcn_s_setprio(1);
                    f32x4 acc = {0.f, 0.f, 0.f, 0.f};
#pragma unroll
                    for (int kc = 0; kc < 4; ++kc) acc = MFMA16(bw[j][kc], a[kc], acc);
                    __builtin_amdgcn_s_setprio(0);

                    const int n = nb + lr;
                    const int cb = wave * 16 + 4 * lg;
                    f16x4 t;
#pragma unroll
                    for (int reg = 0; reg < 4; ++reg) t[reg] = (f16)acc[reg];
                    f16* dst = (j == 0) ? ql : kl;
                    *(f16x4*)&dst[n * 128 + (cb ^ ((n & 7) << 3))] = t;
                }
                {
                    __builtin_amdgcn_s_setprio(1);
                    f32x4 acc = {0.f, 0.f, 0.f, 0.f};
#pragma unroll
                    for (int kc = 0; kc < 4; ++kc) acc = MFMA16(a[kc], bw[2][kc], acc);
                    __builtin_amdgcn_s_setprio(0);

                    const int c = wave * 16 + lr;
                    f16x4 t;
#pragma unroll
                    for (int reg = 0; reg < 4; ++reg) t[reg] = (f16)acc[reg];
                    *(f16x4*)&vl[c * 64 + ((nb + 4 * lg) ^ ((c & 7) << 3))] = t;
                }
            }
        }
        __syncthreads();  // bar1: Q/K/V (both windows) visible; xb consumed

        // restage next pair (latency hides under B/C)
        if (pi + 1 < WPB / 2) {
            stage(wA + 2, 0);
            stage(wA + 3, 1);
        }

        // ===== Phase B, both windows, BOTH HEADS FUSED (swapped QK^T) =====
#pragma unroll
        for (int ws = 0; ws < 2; ++ws) {
            const int w = wA + ws;
            f16* ql = qlds[ws];
            f16* kl = klds[ws];
            f16* vl = vlds[ws];

            const int h0 = 2 * ahh;
            const int h1 = 2 * ahh + 1;

            // mask with k>=49 folded to -1e30 (exp underflow -> exact 0);
            // pad q-rows keep 0 for k<49 so their sums stay > 0 (no NaN).
            const float* mw = mask + (size_t)(w & 63) * (49 * 49);
            float mv[4][4];
#pragma unroll
            for (int reg = 0; reg < 4; ++reg) {
#pragma unroll
                for (int nt = 0; nt < 4; ++nt) {
                    const int k = 4 * lg + reg + 16 * nt;
                    mv[reg][nt] = (k >= 49) ? -1e30f
                                  : (qrow < 49) ? mw[qrow * 49 + k] : 0.f;
                }
            }

            f16x8 aq0 = *(const f16x8*)&ql[qrow * 128 + ((h0 * 32 + 8 * lg) ^ ((qrow & 7) << 3))];
            f16x8 aq1 = *(const f16x8*)&ql[qrow * 128 + ((h1 * 32 + 8 * lg) ^ ((qrow & 7) << 3))];

            // S^T = mfma(K, Q) for both heads
            f32x4 s0[4], s1[4];
            __builtin_amdgcn_s_setprio(1);
#pragma unroll
            for (int nt = 0; nt < 4; ++nt) {
                const int krow = nt * 16 + lr;
                f16x8 bk = *(const f16x8*)&kl[krow * 128 + ((h0 * 32 + 8 * lg) ^ ((krow & 7) << 3))];
                f32x4 z = {0.f, 0.f, 0.f, 0.f};
                s0[nt] = MFMA16(bk, aq0, z);
            }
#pragma unroll
            for (int nt = 0; nt < 4; ++nt) {
                const int krow = nt * 16 + lr;
                f16x8 bk = *(const f16x8*)&kl[krow * 128 + ((h1 * 32 + 8 * lg) ^ ((krow & 7) << 3))];
                f32x4 z = {0.f, 0.f, 0.f, 0.f};
                s1[nt] = MFMA16(bk, aq1, z);
            }
            __builtin_amdgcn_s_setprio(0);

            // exp + in-lane partial sums + vector P stores, both heads
            float sum0 = 0.f, sum1 = 0.f;
#pragma unroll
            for (int nt = 0; nt < 4; ++nt) {
                f16x4 p0t, p1t;
#pragma unroll
                for (int reg = 0; reg < 4; ++reg) {
                    float e0 = __expf(s0[nt][reg] * sc + mv[reg][nt]);
                    float e1 = __expf(s1[nt][reg] * sc + mv[reg][nt]);
                    sum0 += e0;
                    sum1 += e1;
                    p0t[reg] = (f16)e0;
                    p1t[reg] = (f16)e1;
                }
                const int off = lr * 64 + ((4 * lg + 16 * nt) ^ ((lr & 7) << 3));
                *(f16x4*)&ps0[off] = p0t;
                *(f16x4*)&ps1[off] = p1t;
            }
            sum0 += __shfl_xor(sum0, 16, 64);
            sum0 += __shfl_xor(sum0, 32, 64);
            sum1 += __shfl_xor(sum1, 16, 64);
            sum1 += __shfl_xor(sum1, 32, 64);
            const float inv0 = __fdividef(1.f, sum0);
            const float inv1 = __fdividef(1.f, sum1);

            // V fragments under the P-write lgkm shadow
            f16x8 bv0[2][2], bv1[2][2];
#pragma unroll
            for (int nt = 0; nt < 2; ++nt)
#pragma unroll
                for (int kc = 0; kc < 2; ++kc) {
                    const int vr0 = h0 * 32 + nt * 16 + lr;
                    const int vr1 = h1 * 32 + nt * 16 + lr;
                    bv0[nt][kc] = *(const f16x8*)&vl[vr0 * 64 + ((kc * 32 + 8 * lg) ^ ((vr0 & 7) << 3))];
                    bv1[nt][kc] = *(const f16x8*)&vl[vr1 * 64 + ((kc * 32 + 8 * lg) ^ ((vr1 & 7) << 3))];
                }

            // P B-frags (single wait covers both P tiles), PV both heads
            f16x8 ap0[2], ap1[2];
#pragma unroll
            for (int kc = 0; kc < 2; ++kc) {
                const int off = lr * 64 + ((kc * 32 + 8 * lg) ^ ((lr & 7) << 3));
                ap0[kc] = *(const f16x8*)&ps0[off];
                ap1[kc] = *(const f16x8*)&ps1[off];
            }
            f32x4 o00 = {0.f, 0.f, 0.f, 0.f}, o01 = {0.f, 0.f, 0.f, 0.f};
            f32x4 o10 = {0.f, 0.f, 0.f, 0.f}, o11 = {0.f, 0.f, 0.f, 0.f};
            __builtin_amdgcn_s_setprio(1);
#pragma unroll
            for (int kc = 0; kc < 2; ++kc) {
                o00 = MFMA16(bv0[0][kc], ap0[kc], o00);
                o01 = MFMA16(bv0[1][kc], ap0[kc], o01);
                o10 = MFMA16(bv1[0][kc], ap1[kc], o10);
                o11 = MFMA16(bv1[1][kc], ap1[kc], o11);
            }
            __builtin_amdgcn_s_setprio(0);

            // att^T -> qlds[ws]: normalize per-lane, f16x4 stores
            {
                const int n = ar0 + lr;
                const int s = (n & 7) << 3;
                f16x4 t;
#pragma unroll
                for (int reg = 0; reg < 4; ++reg) t[reg] = (f16)(o00[reg] * inv0);
                *(f16x4*)&ql[n * 128 + ((h0 * 32 + 4 * lg) ^ s)] = t;
#pragma unroll
                for (int reg = 0; reg < 4; ++reg) t[reg] = (f16)(o01[reg] * inv0);
                *(f16x4*)&ql[n * 128 + ((h0 * 32 + 16 + 4 * lg) ^ s)] = t;
#pragma unroll
                for (int reg = 0; reg < 4; ++reg) t[reg] = (f16)(o10[reg] * inv1);
                *(f16x4*)&ql[n * 128 + ((h1 * 32 + 4 * lg) ^ s)] = t;
#pragma unroll
                for (int reg = 0; reg < 4; ++reg) t[reg] = (f16)(o11[reg] * inv1);
                *(f16x4*)&ql[n * 128 + ((h1 * 32 + 16 + 4 * lg) ^ s)] = t;
            }
        }
        __syncthreads();  // bar2: att (both windows) complete

        // ===== Phase C, both windows (swapped proj -> float4 stores) ======
#pragma unroll
        for (int ws = 0; ws < 2; ++ws) {
            const f16* ql = qlds[ws];
            float* ob = out + (size_t)(wA + ws) * (49 * 128);
#pragma unroll
            for (int mt = 0; mt < 4; ++mt) {
                const int prow = mt * 16 + lr;
                f16x8 aa[4];
#pragma unroll
                for (int kc = 0; kc < 4; ++kc)
                    aa[kc] = *(const f16x8*)&ql[prow * 128 + ((kc * 32 + 8 * lg) ^ ((prow & 7) << 3))];
                __builtin_amdgcn_s_setprio(1);
                f32x4 acc = {0.f, 0.f, 0.f, 0.f};
#pragma unroll
                for (int kc = 0; kc < 4; ++kc) acc = MFMA16(wpr[kc], aa[kc], acc);
                __builtin_amdgcn_s_setprio(0);

                if (prow < 49) {
                    float4 o;
                    o.x = acc[0] + bcv.x;
                    o.y = acc[1] + bcv.y;
                    o.z = acc[2] + bcv.z;
                    o.w = acc[3] + bcv.w;
                    *(float4*)&ob[prow * 128 + wave * 16 + 4 * lg] = o;
                }
            }
        }
        __syncthreads();  // bar3: q/k/v free for next pair's phase A
    }
}

// ---------------------------------------------------------------------------
// Fallback: fused per-window kernel (no workspace needed).
// ---------------------------------------------------------------------------
template <bool WB>
__global__ __launch_bounds__(256, 4)
void fused_wattn(const float* __restrict__ x, const float* __restrict__ mask,
                 const float* __restrict__ wq_f, const float* __restrict__ wp_f,
                 const f16* __restrict__ wq_h, const f16* __restrict__ wp_h,
                 const float* __restrict__ bias, float* __restrict__ out) {
    __shared__ f16 ks[64 * 128];
    __shared__ f16 vt[128 * 64];
    __shared__ f16 scr[4][1024];

    const int b = blockIdx.x;
    const int wid = b & 63;
    const int tid = threadIdx.x;
    const int wave = tid >> 6;
    const int lane = tid & 63;
    const int lg = lane >> 4;
    const int lr = lane & 15;
    const int r0 = wave * 16;
    f16* ps = scr[wave];

    f16x8 a[4];
    {
        const int xrow = r0 + lr;
        if (xrow < 49) {
            const float* xp = x + ((size_t)b * 49 + xrow) * 128 + 8 * lg;
#pragma unroll
            for (int kc = 0; kc < 4; ++kc) a[kc] = cvt8(xp + kc * 32);
        } else {
            f16x8 z = {0, 0, 0, 0, 0, 0, 0, 0};
#pragma unroll
            for (int kc = 0; kc < 4; ++kc) a[kc] = z;
        }
    }

    float mv[4][4];
#pragma unroll
    for (int reg = 0; reg < 4; ++reg) {
        const int n = r0 + 4 * lg + reg;
#pragma unroll
        for (int nt = 0; nt < 4; ++nt) {
            const int col = nt * 16 + lr;
            mv[reg][nt] = (n < 49 && col < 49) ? mask[((size_t)wid * 49 + n) * 49 + col] : 0.f;
        }
    }

    f16x4 qd[8];
#pragma unroll
    for (int ct = 0; ct < 24; ++ct) {
        const int wrow = ct * 16 + lr;
        f16x8 bw[4];
        if (WB) {
#pragma unroll
            for (int kc = 0; kc < 4; ++kc)
                bw[kc] = *(const f16x8*)&wq_h[wrow * 128 + kc * 32 + 8 * lg];
        } else {
#pragma unroll
            for (int kc = 0; kc < 4; ++kc)
                bw[kc] = cvt8(&wq_f[wrow * 128 + kc * 32 + 8 * lg]);
        }
        f32x4 acc = {0.f, 0.f, 0.f, 0.f};
#pragma unroll
        for (int kc = 0; kc < 4; ++kc) acc = MFMA16(a[kc], bw[kc], acc);

        if (ct < 8) {
            f16x4 q;
#pragma unroll
            for (int reg = 0; reg < 4; ++reg) q[reg] = (f16)acc[reg];
            qd[ct] = q;
        } else if (ct < 16) {
#pragma unroll
            for (int reg = 0; reg < 4; ++reg) {
                const int n = r0 + 4 * lg + reg;
                const int c = wrow - 128;
                ks[n * 128 + (c ^ ((n & 7) << 3))] = (f16)acc[reg];
            }
        } else {
#pragma unroll
            for (int reg = 0; reg < 4; ++reg) {
                const int n = r0 + 4 * lg + reg;
                const int dch = wrow - 256;
                vt[dch * 64 + (n ^ ((dch & 7) << 3))] = (f16)acc[reg];
            }
        }
    }
    __syncthreads();

    const float sc = 0.17677669529663687f;
    f32x4 oacc[4][2];

#pragma unroll
    for (int h = 0; h < 4; ++h) {
#pragma unroll
        for (int c2 = 0; c2 < 2; ++c2)
#pragma unroll
            for (int reg = 0; reg < 4; ++reg) {
                const int row = 4 * lg + reg;
                const int col = c2 * 16 + lr;
                ps[row * 32 + (col ^ ((row & 3) << 3))] = qd[2 * h + c2][reg];
            }
        f16x8 aq = *(const f16x8*)&ps[lr * 32 + ((8 * lg) ^ ((lr & 3) << 3))];

        f32x4 s[4];
#pragma unroll
        for (int nt = 0; nt < 4; ++nt) {
            const int krow = nt * 16 + lr;
            f16x8 bk = *(const f16x8*)&ks[krow * 128 + ((h * 32 + 8 * lg) ^ ((krow & 7) << 3))];
            f32x4 z = {0.f, 0.f, 0.f, 0.f};
            s[nt] = MFMA16(aq, bk, z);
        }

#pragma unroll
        for (int reg = 0; reg < 4; ++reg) {
            float vals[4];
            float sum = 0.f;
#pragma unroll
            for (int nt = 0; nt < 4; ++nt) {
                const int col = nt * 16 + lr;
                float e = (col < 49) ? __expf(s[nt][reg] * sc + mv[reg][nt]) : 0.f;
                vals[nt] = e;
                sum += e;
            }
            for (int d = 1; d < 16; d <<= 1) sum += __shfl_xor(sum, d, 64);
            const float inv = __fdividef(1.f, sum);
            const int row = 4 * lg + reg;
#pragma unroll
            for (int nt = 0; nt < 4; ++nt) {
                const int col = nt * 16 + lr;
                ps[row * 64 + (col ^ ((row & 7) << 3))] = (f16)(vals[nt] * inv);
            }
        }

        f16x8 ap[2];
#pragma unroll
        for (int kc = 0; kc < 2; ++kc)
            ap[kc] = *(const f16x8*)&ps[lr * 64 + ((kc * 32 + 8 * lg) ^ ((lr & 7) << 3))];
#pragma unroll
        for (int nt = 0; nt < 2; ++nt) {
            const int vrow = h * 32 + nt * 16 + lr;
            f32x4 acc = {0.f, 0.f, 0.f, 0.f};
#pragma unroll
            for (int kc = 0; kc < 2; ++kc) {
                f16x8 bv = *(const f16x8*)&vt[vrow * 64 + ((kc * 32 + 8 * lg) ^ ((vrow & 7) << 3))];
                acc = MFMA16(ap[kc], bv, acc);
            }
            oacc[h][nt] = acc;
        }
    }

    f16x8 aa[4];
#pragma unroll
    for (int pass = 0; pass < 2; ++pass) {
#pragma unroll
        for (int h2 = 0; h2 < 2; ++h2)
#pragma unroll
            for (int nt = 0; nt < 2; ++nt)
#pragma unroll
                for (int reg = 0; reg < 4; ++reg) {
                    const int row = 4 * lg + reg;
                    const int col = h2 * 32 + nt * 16 + lr;
                    ps[row * 64 + (col ^ ((row & 7) << 3))] = (f16)oacc[pass * 2 + h2][nt][reg];
                }
#pragma unroll
        for (int kcg = 0; kcg < 2; ++kcg)
            aa[pass * 2 + kcg] = *(const f16x8*)&ps[lr * 64 + ((kcg * 32 + 8 * lg) ^ ((lr & 7) << 3))];
    }

    float* ob = out + (size_t)b * (49 * 128);
#pragma unroll
    for (int ct = 0; ct < 8; ++ct) {
        const int wrow = ct * 16 + lr;
        f16x8 bw[4];
        if (WB) {
#pragma unroll
            for (int kc = 0; kc < 4; ++kc)
                bw[kc] = *(const f16x8*)&wp_h[wrow * 128 + kc * 32 + 8 * lg];
        } else {
#pragma unroll
            for (int kc = 0; kc < 4; ++kc)
                bw[kc] = cvt8(&wp_f[wrow * 128 + kc * 32 + 8 * lg]);
        }
        f32x4 acc = {0.f, 0.f, 0.f, 0.f};
#pragma unroll
        for (int kc = 0; kc < 4; ++kc) acc = MFMA16(aa[kc], bw[kc], acc);

        const float bc = bias[wrow];
#pragma unroll
        for (int reg = 0; reg < 4; ++reg) {
            const int n = r0 + 4 * lg + reg;
            if (n < 49) ob[n * 128 + ct * 16 + lr] = acc[reg] + bc;
        }
    }
}

extern "C" void kernel_launch(void* const* d_in, const int* in_sizes, int n_in,
                              void* d_out, int out_size, void* d_ws, size_t ws_size,
                              hipStream_t stream) {
    const float* x = (const float*)d_in[0];
    const float* mask = (const float*)d_in[1];
    const float* wq = (const float*)d_in[2];
    const float* wp = (const float*)d_in[3];
    const float* bp = (const float*)d_in[4];
    float* out = (float*)d_out;

    const size_t need_wb = (size_t)(49152 + 16384) * sizeof(f16);

    if (ws_size >= need_wb && d_ws != nullptr) {
        f16* wsh = (f16*)d_ws;
        cvt_weights<<<192, 256, 0, stream>>>(wq, wp, wsh);
        fused_all<<<NWIN / WPB, 512, 0, stream>>>(x, mask, wsh, wsh + 49152, bp, out);
    } else {
        fused_wattn<false><<<4096, 256, 0, stream>>>(x, mask, wq, wp, nullptr, nullptr, bp, out);
    }
}